// Round 1
// baseline (1197.962 us; speedup 1.0000x reference)
//
#include <hip/hip_runtime.h>
#include <stdint.h>

// CTC forward NLL, B=32, T=2000, V=1024, S=128, L=2S+1=257.
// FUSED producer/consumer single kernel:
//  - blocks 0..31: per-batch DP consumer (1 wave), register-ring prefetch of
//    label rows via asm global_load_dwordx2 sc0 sc1 (device-coherence-point
//    reads), paced by counted s_waitcnt vmcnt(N); per-section flag poll folded
//    into the vmcnt stream; blank probs via double-buffered s_load (lgkmcnt).
//  - blocks 32..10719: producers, one (b, 6-row group) each, dispatched in
//    ascending-t order: stage 24KB of log-probs to LDS, gather+exp 6x128
//    labels + 6 blank probs, publish flag with atomic-release (agent scope).
// Producers never wait -> deadlock-free regardless of dispatch order.
// vmcnt bookkeeping: 6 ring + 1 flag load per section, ring depth 8 ->
// steady outstanding 56, wait 49 drains current chunk (6) + the 8-section-old
// flag (1). Prologue waits 43..49 (no flag history yet).

#define LOG2E_F 1.4426950408889634f
#define LN2_F   0.6931471805599453f

constexpr int CB = 32;       // batch
constexpr int CT = 2000;     // time
constexpr int CV = 1024;     // vocab
constexpr int CS = 128;      // max target len
constexpr int RF = 128;      // floats per label row (512 B)
constexpr int GR = 6;        // rows per producer group (= DP chunk size)
constexpr int NGRP = (CT + GR - 1) / GR;   // 334 groups per batch
constexpr float PMIN = 9.5367431640625e-07f;  // 2^-20

// ---------------- DPP helpers ----------------
__device__ __forceinline__ float dpp_wshr1(float x) {   // lane n <- lane n-1, lane0 <- 0
    return __int_as_float(__builtin_amdgcn_update_dpp(
        0, __float_as_int(x), 0x138, 0xF, 0xF, true));
}
__device__ __forceinline__ int dpp_wshr1_i(int x) {
    return __builtin_amdgcn_update_dpp(0, x, 0x138, 0xF, 0xF, true);
}

// ---------------- DP core ----------------
__device__ __forceinline__ void run6(const float2 (&lab)[6], const float (&pv)[6],
                                     float& a0, float& a1, float& a2, float& a3,
                                     float& aX, float msk1, float msk3, float f) {
#pragma unroll
    for (int u = 0; u < 6; ++u) {
        const float pb = pv[u];
        const float u3 = dpp_wshr1(a3) * f;              // old alpha[4i-1], rescaled
        const float n0 = (a0 + u3) * pb;                 // blank 4i
        const float n1 = fmaf(msk1, u3, a1 + a0) * lab[u].x;  // label s=2i
        const float n2 = (a2 + a1) * pb;                 // blank 4i+2
        const float n3 = fmaf(msk3, a1, a3 + a2) * lab[u].y;  // label s=2i+1
        const float nX = (aX + a3) * pb;                 // cell 256 (lane 63 only valid)
        a0 = n0; a1 = n1; a2 = n2; a3 = n3; aX = nX;
    }
}

__device__ __forceinline__ void renorm(float& a0, float& a1, float& a2,
                                       float& a3, float& aX, int& Sc, float& f) {
    const float m = fmaxf(fmaxf(fmaxf(a0, a1), fmaxf(a2, a3)), aX);
    const bool active = (m > 0.f);
    const int E = active ? (((__float_as_int(m) >> 23) & 0xFF) - 126) : 0;
    const float s = __int_as_float((127 - E) << 23);   // exact 2^-E
    a0 *= s; a1 *= s; a2 *= s; a3 *= s; aX *= s;
    Sc += E;
#pragma unroll
    for (int k = 0; k < 4; ++k) {
        const int scl = dpp_wshr1_i(Sc);
        Sc = active ? Sc : scl;
    }
    int d = dpp_wshr1_i(Sc) - Sc;
    d = min(126, max(-126, d));
    f = __int_as_float((d + 127) << 23);               // exact 2^d
}

// ---------------- consumer macros ----------------
// 6 coalesced 8B-per-lane ring loads, device-coherence-point reads
#define PF6(SLOT, cc) do {                                                           \
    const float* _s = lab_base + (size_t)(1 + 6 * (size_t)(cc)) * RF + 2 * lane;     \
    asm volatile("global_load_dwordx2 %0, %1, off sc0 sc1" : "=v"(rg[SLOT][0]) : "v"(_s));          \
    asm volatile("global_load_dwordx2 %0, %1, off sc0 sc1" : "=v"(rg[SLOT][1]) : "v"(_s + RF));     \
    asm volatile("global_load_dwordx2 %0, %1, off sc0 sc1" : "=v"(rg[SLOT][2]) : "v"(_s + 2 * RF)); \
    asm volatile("global_load_dwordx2 %0, %1, off sc0 sc1" : "=v"(rg[SLOT][3]) : "v"(_s + 3 * RF)); \
    asm volatile("global_load_dwordx2 %0, %1, off sc0 sc1" : "=v"(rg[SLOT][4]) : "v"(_s + 4 * RF)); \
    asm volatile("global_load_dwordx2 %0, %1, off sc0 sc1" : "=v"(rg[SLOT][5]) : "v"(_s + 5 * RF)); \
  } while (0)

// pipelined flag poll for group c+16, consumed 8 sections later
#define FPOLL(SLOT) do {                                                             \
    unsigned int* _fa = flg + min(c + 16, NGRP - 1);                                 \
    asm volatile("global_load_dword %0, %1, off sc0 sc1" : "=v"(fr[SLOT]) : "v"(_fa)); \
  } while (0)

#define WAITC(SLOT, WN)                                                              \
    asm volatile("s_waitcnt vmcnt(" #WN ")"                                          \
                 : "+v"(rg[SLOT][0]), "+v"(rg[SLOT][1]), "+v"(rg[SLOT][2]),          \
                   "+v"(rg[SLOT][3]), "+v"(rg[SLOT][4]), "+v"(rg[SLOT][5]),          \
                   "+v"(fr[((SLOT) + 1) & 7]))

// blank probs: 6 scalar loads (lgkmcnt counter - does not perturb vmcnt ring)
#define PBLOAD(QN, cc) do {                                                          \
    const unsigned long long _pa = (unsigned long long)(pb_base + 1 + 6 * (size_t)(cc)); \
    asm volatile("s_load_dword %0, %6, 0x0\n\t"                                      \
                 "s_load_dword %1, %6, 0x4\n\t"                                      \
                 "s_load_dword %2, %6, 0x8\n\t"                                      \
                 "s_load_dword %3, %6, 0xc\n\t"                                      \
                 "s_load_dword %4, %6, 0x10\n\t"                                     \
                 "s_load_dword %5, %6, 0x14"                                         \
                 : "=&s"(q[QN][0]), "=&s"(q[QN][1]), "=&s"(q[QN][2]),                \
                   "=&s"(q[QN][3]), "=&s"(q[QN][4]), "=&s"(q[QN][5])                 \
                 : "s"(_pa));                                                        \
  } while (0)

#define PBWAIT(QC)                                                                   \
    asm volatile("s_waitcnt lgkmcnt(0)"                                              \
                 : "+s"(q[QC][0]), "+s"(q[QC][1]), "+s"(q[QC][2]),                   \
                   "+s"(q[QC][3]), "+s"(q[QC][4]), "+s"(q[QC][5]))

#define SBODY(SLOT, WN, QC, QN)                                                      \
    if (__builtin_expect(fr[SLOT] == 0, 0)) {                                        \
        unsigned int* _fb = flg + min(c + 8, NGRP - 1);                              \
        while (__hip_atomic_load(_fb, __ATOMIC_ACQUIRE, __HIP_MEMORY_SCOPE_AGENT) == 0u) {} \
        fr[SLOT] = 1;                                                                \
    }                                                                                \
    PF6(((SLOT) + 7) & 7, min(c + 7, NCm1));                                         \
    FPOLL(SLOT);                                                                     \
    WAITC(SLOT, WN);                                                                 \
    PBWAIT(QC);                                                                      \
    PBLOAD(QN, min(c + 1, NCm1));                                                    \
    {                                                                                \
        const float pv[6] = {                                                        \
            __uint_as_float(q[QC][0]), __uint_as_float(q[QC][1]),                    \
            __uint_as_float(q[QC][2]), __uint_as_float(q[QC][3]),                    \
            __uint_as_float(q[QC][4]), __uint_as_float(q[QC][5]) };                  \
        run6(rg[SLOT], pv, a0, a1, a2, a3, aX, msk1, msk3, f);                       \
        renorm(a0, a1, a2, a3, aX, Sc, f);                                           \
    }

#define SECTION_P(SLOT, WN, QC, QN) { SBODY(SLOT, WN, QC, QN); ++c; }
#define SECTION_L(SLOT, WN, QC, QN) { SBODY(SLOT, WN, QC, QN); if (++c >= NC) break; }

// ---------------- fused kernel ----------------
__global__ __launch_bounds__(256) void ctc_fused(
        const float* __restrict__ lp, const int* __restrict__ targets,
        const int* __restrict__ in_len, const int* __restrict__ tg_len,
        float* __restrict__ labels, float* __restrict__ pbuf,
        unsigned int* __restrict__ flags, float* __restrict__ out) {

    if (blockIdx.x >= (unsigned)CB) {
        // ---------------- producer: one (b, 6-row group) ----------------
        __shared__ float rows[GR * CV];                 // 24 KB
        const int task = blockIdx.x - CB;
        const int g = task >> 5;                        // group index, ascending with blockIdx
        const int b = task & 31;
        const int t0 = g * GR;
        const int nr = min(GR, CT - t0);
        const int tid = threadIdx.x;
        const float* src = lp + ((size_t)b * CT + t0) * CV;
        const int nf4 = nr * (CV / 4);
        for (int i = tid; i < nf4; i += 256)
            ((float4*)rows)[i] = ((const float4*)src)[i];
        __syncthreads();
        float* ldst = labels + ((size_t)b * CT + t0) * RF;
        const int nlab = nr * RF;
        for (int i = tid; i < nlab; i += 256) {
            const int tg = targets[b * CS + (i & 127)];
            ldst[i] = fmaxf(exp2f(rows[(i >> 7) * CV + tg] * LOG2E_F), PMIN);
        }
        if (tid < nr)
            pbuf[(size_t)b * CT + t0 + tid] = fmaxf(exp2f(rows[tid * CV] * LOG2E_F), PMIN);
        __syncthreads();   // per-wave vmcnt(0) drain of all stores
        if (tid == 0) {
            __threadfence();
            __hip_atomic_store(&flags[b * NGRP + g], 1u,
                               __ATOMIC_RELEASE, __HIP_MEMORY_SCOPE_AGENT);
        }
        return;
    }

    // ---------------- consumer: per-batch DP ----------------
    if (threadIdx.x >= 64) return;
    __builtin_amdgcn_s_setprio(1);   // win VALU issue vs co-resident producer waves
    const int b = blockIdx.x;
    const int lane = threadIdx.x;            // 0..63, owns cells 4i..4i+3
    const int Tb = in_len[b];
    const int Sb = tg_len[b];
    const float* lab_base = labels + (size_t)b * CT * RF;
    const float* pb_base  = pbuf + (size_t)b * CT;
    unsigned int* flg = flags + b * NGRP;

    const int tg0 = targets[b * CS + 2 * lane];
    const int tg1 = targets[b * CS + 2 * lane + 1];
    const int tgm = dpp_wshr1_i(tg1);        // targets[2i-1] (lane0: 0)
    const float msk1 = (tg0 != tgm) ? 1.f : 0.f;
    const float msk3 = (tg1 != tg0) ? 1.f : 0.f;

    // blocking-confirm groups 0..15 (init + warmup + prologue fr-prime coverage)
    for (int g = 0; g < 16; ++g) {
        unsigned int* fa = flg + min(g, NGRP - 1);
        while (__hip_atomic_load(fa, __ATOMIC_ACQUIRE, __HIP_MEMORY_SCOPE_AGENT) == 0u) {}
    }

    // t=0 init: alpha[0]=p_blank, alpha[1]=p(label 0)
    float a0 = 0.f, a1 = 0.f, a2 = 0.f, a3 = 0.f, aX = 0.f;
    {
        const float pb0 = pb_base[0];
        const float pl0 = lab_base[0];
        if (lane == 0) { a0 = pb0; a1 = pl0; }
    }
    int Sc = 0;
    float f = 1.f;
    renorm(a0, a1, a2, a3, aX, Sc, f);

    const int NC = (Tb - 1) / 6;             // full 6-step chunks from t=1
    const int NCm1 = NC - 1;
    float2 rg[8][6];                          // 96-VGPR register ring
    int fr[8];                                // flag-poll ring
    unsigned int q[2][6];                     // pb double buffer (SGPRs)

    if (NC >= 9) {
#pragma unroll
        for (int s = 0; s < 8; ++s) fr[s] = 1;   // groups <=15 already confirmed
        PBLOAD(0, 0);
        PF6(0, 0); PF6(1, 1); PF6(2, 2); PF6(3, 3); PF6(4, 4); PF6(5, 5); PF6(6, 6);
        int c = 0;
        // prologue: flag history not yet built -> waits 43..49
        SECTION_P(0, 43, 0, 1) SECTION_P(1, 44, 1, 0)
        SECTION_P(2, 45, 0, 1) SECTION_P(3, 46, 1, 0)
        SECTION_P(4, 47, 0, 1) SECTION_P(5, 48, 1, 0)
        SECTION_P(6, 49, 0, 1) SECTION_P(7, 49, 1, 0)
        while (true) {
            SECTION_L(0, 49, 0, 1) SECTION_L(1, 49, 1, 0)
            SECTION_L(2, 49, 0, 1) SECTION_L(3, 49, 1, 0)
            SECTION_L(4, 49, 0, 1) SECTION_L(5, 49, 1, 0)
            SECTION_L(6, 49, 0, 1) SECTION_L(7, 49, 1, 0)
        }
    } else if (NC >= 1) {
        // tiny-T fallback: compiler-managed loads, blocking polls
        for (int cc = 0; cc < NC; ++cc) {
            unsigned int* fa = flg + min(cc + 1, NGRP - 1);
            while (__hip_atomic_load(fa, __ATOMIC_ACQUIRE, __HIP_MEMORY_SCOPE_AGENT) == 0u) {}
            const int toff = 1 + 6 * cc;
            float2 lb[6]; float pv[6];
#pragma unroll
            for (int u = 0; u < 6; ++u) {
                lb[u] = *(const float2*)(lab_base + (size_t)(toff + u) * RF + 2 * lane);
                pv[u] = pb_base[toff + u];
            }
            run6(lb, pv, a0, a1, a2, a3, aX, msk1, msk3, f);
            renorm(a0, a1, a2, a3, aX, Sc, f);
        }
    }

    // confirm final group for tail rows (no-op in steady operation)
    {
        unsigned int* fa = flg + min((Tb - 1) / GR, NGRP - 1);
        while (__hip_atomic_load(fa, __ATOMIC_ACQUIRE, __HIP_MEMORY_SCOPE_AGENT) == 0u) {}
    }
    // tail: t = 1+6*NC .. Tb-1 (<=5 steps); compiler drains ring before its loads
    for (int t = 1 + 6 * NC; t < Tb; ++t) {
        const float2 lb = *(const float2*)(lab_base + (size_t)t * RF + 2 * lane);
        const float pb = pb_base[t];
        const float u3 = dpp_wshr1(a3) * f;
        const float n0 = (a0 + u3) * pb;
        const float n1 = fmaf(msk1, u3, a1 + a0) * lb.x;
        const float n2 = (a2 + a1) * pb;
        const float n3 = fmaf(msk3, a1, a3 + a2) * lb.y;
        const float nX = (aX + a3) * pb;
        a0 = n0; a1 = n1; a2 = n2; a3 = n3; aX = nX;
    }

    // final: ll = log(alpha[2*Sb] + alpha[2*Sb-1]); per-lane scales -> LSE
    const int idx1 = 2 * Sb;
    const int idx2 = (idx1 - 1 > 0) ? (idx1 - 1) : 0;
    const int b4 = 4 * lane;
    float cres = 0.f;
    if (b4 + 0 == idx1 || b4 + 0 == idx2) cres += a0;
    if (b4 + 1 == idx1 || b4 + 1 == idx2) cres += a1;
    if (b4 + 2 == idx1 || b4 + 2 == idx2) cres += a2;
    if (b4 + 3 == idx1 || b4 + 3 == idx2) cres += a3;
    if (lane == 63 && (idx1 == 256 || idx2 == 256)) cres += aX;

    float l2 = (cres > 0.f) ? (log2f(cres) + (float)Sc) : -1e30f;
    float M = l2;
#pragma unroll
    for (int m = 1; m < 64; m <<= 1) M = fmaxf(M, __shfl_xor(M, m, 64));
    float e = (cres > 0.f) ? exp2f(l2 - M) : 0.f;
#pragma unroll
    for (int m = 1; m < 64; m <<= 1) e += __shfl_xor(e, m, 64);
    if (lane == 0) {
        const float ll = (M + log2f(e)) * LN2_F;
        atomicAdd(out, -ll);
    }
}

extern "C" void kernel_launch(void* const* d_in, const int* in_sizes, int n_in,
                              void* d_out, int out_size, void* d_ws, size_t ws_size,
                              hipStream_t stream) {
    (void)in_sizes; (void)n_in; (void)out_size; (void)ws_size;
    const float* lp      = (const float*)d_in[0];
    const int*   targets = (const int*)d_in[1];
    const int*   in_len  = (const int*)d_in[2];
    const int*   tg_len  = (const int*)d_in[3];
    float* out    = (float*)d_out;
    float* labels = (float*)d_ws;                               // 32.77 MB
    float* pbuf   = labels + (size_t)CB * CT * RF;              // +256 KB
    unsigned int* flags = (unsigned int*)(pbuf + (size_t)CB * CT);  // +42.8 KB

    // flags must start at 0 (workspace is poisoned each iteration)
    hipMemsetAsync(flags, 0, (size_t)CB * NGRP * sizeof(unsigned int), stream);
    hipMemsetAsync(out, 0, sizeof(float), stream);
    ctc_fused<<<dim3(CB + CB * NGRP), dim3(256), 0, stream>>>(
        lp, targets, in_len, tg_len, labels, pbuf, flags, out);
}

// Round 3
// 507.658 us; speedup vs baseline: 2.3598x; 2.3598x over previous
//
#include <hip/hip_runtime.h>
#include <stdint.h>

// CTC forward NLL, B=32, T=2000, V=1024, S=128, L=2S+1=257.
// Single kernel: 32 blocks x 1 wave. Each wave streams its batch's log-prob
// rows (4 KB each) straight from HBM into a 4-slot LDS ring (24 x
// global_load_lds_dwordx4 per 6-row chunk, in-order vmcnt pacing at 24/48),
// gathers the 129 needed entries per row via pipelined ds_read_b32 (lgkmcnt
// pacing -- 4-bit field, max 15! -- split 12+6 so the counted wait is 12),
// applies exp2f+clamp at consume time, and runs the proven linear-domain DP
// (per-lane block-floating-point, DPP neighbor exchange). No intermediate
// labels buffer, no second kernel, no cross-workgroup coherence.
// Ordering discipline: LDS-DMA via the tracked builtin; all waits are
// volatile asm with dependent registers tied ("+v"); stok data-chains the
// staging addresses after the most recent wait; post-loop full drain +
// keep-alive ties prevent late ds_read completions from clobbering
// reallocated registers.

#define LOG2E_F 1.4426950408889634f
#define LN2_F   0.6931471805599453f

constexpr int CB = 32;       // batch
constexpr int CT = 2000;     // time
constexpr int CV = 1024;     // vocab
constexpr int CS = 128;      // max target len
constexpr float PMIN = 9.5367431640625e-07f;  // 2^-20: 6-step window >= 2^-120

typedef __attribute__((address_space(3))) float lds_float;
typedef __attribute__((address_space(1))) const void gconst_void;

// ---------------- DPP helpers ----------------
__device__ __forceinline__ float dpp_wshr1(float x) {   // lane n <- lane n-1, lane0 <- 0
    return __int_as_float(__builtin_amdgcn_update_dpp(
        0, __float_as_int(x), 0x138, 0xF, 0xF, true));
}
__device__ __forceinline__ int dpp_wshr1_i(int x) {
    return __builtin_amdgcn_update_dpp(0, x, 0x138, 0xF, 0xF, true);
}

// ---------------- DP core ----------------
__device__ __forceinline__ void run6b(const float (&l0)[6], const float (&l1)[6],
                                      const float (&pp)[6],
                                      float& a0, float& a1, float& a2, float& a3,
                                      float& aX, float msk1, float msk3, float f) {
#pragma unroll
    for (int u = 0; u < 6; ++u) {
        const float pb = pp[u];
        const float u3 = dpp_wshr1(a3) * f;              // old alpha[4i-1], rescaled
        const float n0 = (a0 + u3) * pb;                 // blank 4i
        const float n1 = fmaf(msk1, u3, a1 + a0) * l0[u];  // label s=2i
        const float n2 = (a2 + a1) * pb;                 // blank 4i+2
        const float n3 = fmaf(msk3, a1, a3 + a2) * l1[u];  // label s=2i+1
        const float nX = (aX + a3) * pb;                 // cell 256 (lane 63 only valid)
        a0 = n0; a1 = n1; a2 = n2; a3 = n3; aX = nX;
    }
}

__device__ __forceinline__ void renorm(float& a0, float& a1, float& a2,
                                       float& a3, float& aX, int& Sc, float& f) {
    const float m = fmaxf(fmaxf(fmaxf(a0, a1), fmaxf(a2, a3)), aX);
    const bool active = (m > 0.f);
    const int E = active ? (((__float_as_int(m) >> 23) & 0xFF) - 126) : 0;
    const float s = __int_as_float((127 - E) << 23);   // exact 2^-E
    a0 *= s; a1 *= s; a2 *= s; a3 *= s; aX *= s;
    Sc += E;
#pragma unroll
    for (int k = 0; k < 4; ++k) {
        const int scl = dpp_wshr1_i(Sc);
        Sc = active ? Sc : scl;
    }
    int d = dpp_wshr1_i(Sc) - Sc;
    d = min(126, max(-126, d));
    f = __int_as_float((d + 127) << 23);               // exact 2^d
}

// ---------------- staging / gather macros ----------------
// Stage 6-row chunk KK into ring slot SLOT: 24 x global_load_lds_dwordx4.
// LDS dest is wave-uniform (HW adds lane*16); global src is per-lane.
// stok (always 0) data-chains the address calc after the most recent wait.
#define STAGE(SLOT, KK) do {                                                        \
    const float* _g = lp1 + (size_t)6144 * (size_t)(KK) + 4 * lane + stok;          \
    lds_float* _l = rp3 + (SLOT) * 6144;                                            \
    _Pragma("unroll")                                                               \
    for (int _i = 0; _i < 24; ++_i)                                                 \
        __builtin_amdgcn_global_load_lds(                                           \
            (gconst_void*)(_g + 256 * _i),                                          \
            (__attribute__((address_space(3))) void*)(_l + 256 * _i), 16, 0, 0);    \
} while (0)

// Gather the 12 label entries (rows 0..5 at tg0, tg1) of slot SLOT.
#define GATHER12(L0, L1, SLOT) do {                                                 \
    const unsigned _sb = rbase + (unsigned)(SLOT) * 24576u;                         \
    const unsigned _g0 = _sb + 4u * (unsigned)tg0;                                  \
    const unsigned _g1 = _sb + 4u * (unsigned)tg1;                                  \
    asm volatile("ds_read_b32 %0, %1"              : "=v"(L0[0]) : "v"(_g0));       \
    asm volatile("ds_read_b32 %0, %1 offset:4096"  : "=v"(L0[1]) : "v"(_g0));       \
    asm volatile("ds_read_b32 %0, %1 offset:8192"  : "=v"(L0[2]) : "v"(_g0));       \
    asm volatile("ds_read_b32 %0, %1 offset:12288" : "=v"(L0[3]) : "v"(_g0));       \
    asm volatile("ds_read_b32 %0, %1 offset:16384" : "=v"(L0[4]) : "v"(_g0));       \
    asm volatile("ds_read_b32 %0, %1 offset:20480" : "=v"(L0[5]) : "v"(_g0));       \
    asm volatile("ds_read_b32 %0, %1"              : "=v"(L1[0]) : "v"(_g1));       \
    asm volatile("ds_read_b32 %0, %1 offset:4096"  : "=v"(L1[1]) : "v"(_g1));       \
    asm volatile("ds_read_b32 %0, %1 offset:8192"  : "=v"(L1[2]) : "v"(_g1));       \
    asm volatile("ds_read_b32 %0, %1 offset:12288" : "=v"(L1[3]) : "v"(_g1));       \
    asm volatile("ds_read_b32 %0, %1 offset:16384" : "=v"(L1[4]) : "v"(_g1));       \
    asm volatile("ds_read_b32 %0, %1 offset:20480" : "=v"(L1[5]) : "v"(_g1));       \
} while (0)

// Gather the 6 blank entries (vocab idx 0, uniform -> broadcast) of slot SLOT.
#define GATHER6(LP, SLOT) do {                                                      \
    const unsigned _sb = rbase + (unsigned)(SLOT) * 24576u;                         \
    asm volatile("ds_read_b32 %0, %1"              : "=v"(LP[0]) : "v"(_sb));       \
    asm volatile("ds_read_b32 %0, %1 offset:4096"  : "=v"(LP[1]) : "v"(_sb));       \
    asm volatile("ds_read_b32 %0, %1 offset:8192"  : "=v"(LP[2]) : "v"(_sb));       \
    asm volatile("ds_read_b32 %0, %1 offset:12288" : "=v"(LP[3]) : "v"(_sb));       \
    asm volatile("ds_read_b32 %0, %1 offset:16384" : "=v"(LP[4]) : "v"(_sb));       \
    asm volatile("ds_read_b32 %0, %1 offset:20480" : "=v"(LP[5]) : "v"(_sb));       \
} while (0)

// Wait until <=24 vmem outstanding -> chunk c+1 fully landed in LDS.
// Ties the NEXT bank's regs (WAR: the following gathers must stay after)
// and stok (the following STAGE's addresses must stay after).
#define WAITV24(N0, N1, NP)                                                         \
    asm volatile("s_waitcnt vmcnt(24)"                                              \
        : "+v"(stok),                                                               \
          "+v"(N0[0]), "+v"(N0[1]), "+v"(N0[2]), "+v"(N0[3]), "+v"(N0[4]), "+v"(N0[5]), \
          "+v"(N1[0]), "+v"(N1[1]), "+v"(N1[2]), "+v"(N1[3]), "+v"(N1[4]), "+v"(N1[5]), \
          "+v"(NP[0]), "+v"(NP[1]), "+v"(NP[2]), "+v"(NP[3]), "+v"(NP[4]), "+v"(NP[5]))

// Steady state at this wait: oldest 18 DS ops = current bank (12 issued in
// previous section + 6 issued after previous consume); newest 12 = next
// bank's GATHER12 just issued. lgkmcnt(12) -> current bank complete.
// (lgkmcnt is a 4-BIT field on gfx9: values must be <= 15.)
#define DSWAIT12(L0, L1, LP)                                                        \
    asm volatile("s_waitcnt lgkmcnt(12)"                                            \
        : "+v"(L0[0]), "+v"(L0[1]), "+v"(L0[2]), "+v"(L0[3]), "+v"(L0[4]), "+v"(L0[5]), \
          "+v"(L1[0]), "+v"(L1[1]), "+v"(L1[2]), "+v"(L1[3]), "+v"(L1[4]), "+v"(L1[5]), \
          "+v"(LP[0]), "+v"(LP[1]), "+v"(LP[2]), "+v"(LP[3]), "+v"(LP[4]), "+v"(LP[5]))

// One 6-step section for chunk c (consumes bank C, prefetches bank N=c+1):
// wait chunk c+1 landed -> stage c+3 -> gather12 c+1 -> wait bank C ->
// exp+clamp -> DP -> renorm -> gather6 (blank) c+1.
#define SECTION(SLOT, C0, C1, CP, N0, N1, NP) {                                     \
    WAITV24(N0, N1, NP);                                                            \
    STAGE((((SLOT) + 3) & 3), min(c + 3, NSm1));                                    \
    GATHER12(N0, N1, (((SLOT) + 1) & 3));                                           \
    DSWAIT12(C0, C1, CP);                                                           \
    _Pragma("unroll")                                                               \
    for (int _u = 0; _u < 6; ++_u) {                                                \
        C0[_u] = fmaxf(exp2f(C0[_u] * LOG2E_F), PMIN);                              \
        C1[_u] = fmaxf(exp2f(C1[_u] * LOG2E_F), PMIN);                              \
        CP[_u] = fmaxf(exp2f(CP[_u] * LOG2E_F), PMIN);                              \
    }                                                                               \
    run6b(C0, C1, CP, a0, a1, a2, a3, aX, msk1, msk3, f);                           \
    renorm(a0, a1, a2, a3, aX, Sc, f);                                              \
    GATHER6(NP, (((SLOT) + 1) & 3));                                                \
    if (++c >= NC) break;                                                           \
}

// ---------------- the kernel ----------------
__global__ __launch_bounds__(64) void ctc_dp(
        const float* __restrict__ lp, const int* __restrict__ targets,
        const int* __restrict__ in_len, const int* __restrict__ tg_len,
        float* __restrict__ out) {
    __shared__ float ring[4][6144];          // 96 KB: 4 slots x 6 rows x 4 KB
    const int b = blockIdx.x;
    const int lane = threadIdx.x;            // 0..63, owns cells 4i..4i+3
    const int Tb = in_len[b];
    const int Sb = tg_len[b];
    const float* lp0 = lp + (size_t)b * CT * CV;   // row t=0
    const float* lp1 = lp0 + CV;                   // row t=1 (chunk base)

    const int tg0 = targets[b * CS + 2 * lane];
    const int tg1 = targets[b * CS + 2 * lane + 1];
    const int tgm = dpp_wshr1_i(tg1);        // targets[2i-1] (lane0: 0)
    const float msk1 = (tg0 != tgm) ? 1.f : 0.f;
    const float msk3 = (tg1 != tg0) ? 1.f : 0.f;

    // t=0 init: alpha[0]=p_blank, alpha[1]=p(label 0)
    float a0 = 0.f, a1 = 0.f, a2 = 0.f, a3 = 0.f, aX = 0.f;
    if (lane == 0) {
        a0 = fmaxf(exp2f(lp0[0] * LOG2E_F), PMIN);
        a1 = fmaxf(exp2f(lp0[tg0] * LOG2E_F), PMIN);
    }
    int Sc = 0;
    float f = 1.f;
    renorm(a0, a1, a2, a3, aX, Sc, f);

    lds_float* rp3 = (lds_float*)&ring[0][0];
    const unsigned rbase = (unsigned)(uintptr_t)rp3;

    const int NC = (Tb - 1) / 6;             // full 6-step chunks from t=1
    const int NSm1 = NC - 1;
    int stok = 0;                            // ordering token (always 0)

    float A0[6] = {0}, A1[6] = {0}, AP[6] = {0};
    float B0[6] = {0}, B1[6] = {0}, BP[6] = {0};

    if (NC >= 1) {
        // clean counter baseline: all pre-loop loads drained
        asm volatile("s_waitcnt vmcnt(0) lgkmcnt(0)" : "+v"(stok));
        STAGE(0, 0);
        STAGE(1, min(1, NSm1));
        STAGE(2, min(2, NSm1));
        // chunk 0 landed (72 issued, wait to 48 -> oldest 24 done)
        asm volatile("s_waitcnt vmcnt(48)"
            : "+v"(stok),
              "+v"(A0[0]), "+v"(A0[1]), "+v"(A0[2]), "+v"(A0[3]), "+v"(A0[4]), "+v"(A0[5]),
              "+v"(A1[0]), "+v"(A1[1]), "+v"(A1[2]), "+v"(A1[3]), "+v"(A1[4]), "+v"(A1[5]),
              "+v"(AP[0]), "+v"(AP[1]), "+v"(AP[2]), "+v"(AP[3]), "+v"(AP[4]), "+v"(AP[5]));
        GATHER12(A0, A1, 0);
        GATHER6(AP, 0);
        int c = 0;
        while (true) {
            SECTION(0, A0, A1, AP, B0, B1, BP)
            SECTION(1, B0, B1, BP, A0, A1, AP)
            SECTION(2, A0, A1, AP, B0, B1, BP)
            SECTION(3, B0, B1, BP, A0, A1, AP)
        }
        // Drain everything still in flight (<=18 ds_reads + <=48 LDS-DMA),
        // then keep the bank registers alive past the drain so late DS
        // completions cannot clobber reallocated registers (volatile asm
        // order is preserved; liveness spans the drain).
        asm volatile("s_waitcnt vmcnt(0) lgkmcnt(0)" : "+v"(stok));
        asm volatile("" ::
            "v"(A0[0]), "v"(A0[1]), "v"(A0[2]), "v"(A0[3]), "v"(A0[4]), "v"(A0[5]),
            "v"(A1[0]), "v"(A1[1]), "v"(A1[2]), "v"(A1[3]), "v"(A1[4]), "v"(A1[5]),
            "v"(AP[0]), "v"(AP[1]), "v"(AP[2]), "v"(AP[3]), "v"(AP[4]), "v"(AP[5]));
        asm volatile("" ::
            "v"(B0[0]), "v"(B0[1]), "v"(B0[2]), "v"(B0[3]), "v"(B0[4]), "v"(B0[5]),
            "v"(B1[0]), "v"(B1[1]), "v"(B1[2]), "v"(B1[3]), "v"(B1[4]), "v"(B1[5]),
            "v"(BP[0]), "v"(BP[1]), "v"(BP[2]), "v"(BP[3]), "v"(BP[4]), "v"(BP[5]));
    }

    // tail: t = 1+6*NC .. Tb-1 (<=5 steps); direct global reads (all asm
    // ring traffic fully drained above).
    for (int t = 1 + 6 * NC; t < Tb; ++t) {
        const float* rowp = lp0 + (size_t)t * CV;
        const float lx = fmaxf(exp2f(rowp[tg0] * LOG2E_F), PMIN);
        const float ly = fmaxf(exp2f(rowp[tg1] * LOG2E_F), PMIN);
        const float pb = fmaxf(exp2f(rowp[0] * LOG2E_F), PMIN);
        const float u3 = dpp_wshr1(a3) * f;
        const float n0 = (a0 + u3) * pb;
        const float n1 = fmaf(msk1, u3, a1 + a0) * lx;
        const float n2 = (a2 + a1) * pb;
        const float n3 = fmaf(msk3, a1, a3 + a2) * ly;
        const float nX = (aX + a3) * pb;
        a0 = n0; a1 = n1; a2 = n2; a3 = n3; aX = nX;
    }

    // final: ll = log(alpha[2*Sb] + alpha[2*Sb-1]); per-lane scales -> LSE
    const int idx1 = 2 * Sb;
    const int idx2 = (idx1 - 1 > 0) ? (idx1 - 1) : 0;
    const int b4 = 4 * lane;
    float cres = 0.f;
    if (b4 + 0 == idx1 || b4 + 0 == idx2) cres += a0;
    if (b4 + 1 == idx1 || b4 + 1 == idx2) cres += a1;
    if (b4 + 2 == idx1 || b4 + 2 == idx2) cres += a2;
    if (b4 + 3 == idx1 || b4 + 3 == idx2) cres += a3;
    if (lane == 63 && (idx1 == 256 || idx2 == 256)) cres += aX;

    float l2 = (cres > 0.f) ? (log2f(cres) + (float)Sc) : -1e30f;
    float M = l2;
#pragma unroll
    for (int m = 1; m < 64; m <<= 1) M = fmaxf(M, __shfl_xor(M, m, 64));
    float e = (cres > 0.f) ? exp2f(l2 - M) : 0.f;
#pragma unroll
    for (int m = 1; m < 64; m <<= 1) e += __shfl_xor(e, m, 64);
    if (lane == 0) {
        const float ll = (M + log2f(e)) * LN2_F;
        atomicAdd(out, -ll);
    }
}

extern "C" void kernel_launch(void* const* d_in, const int* in_sizes, int n_in,
                              void* d_out, int out_size, void* d_ws, size_t ws_size,
                              hipStream_t stream) {
    (void)in_sizes; (void)n_in; (void)out_size; (void)d_ws; (void)ws_size;
    const float* lp      = (const float*)d_in[0];
    const int*   targets = (const int*)d_in[1];
    const int*   in_len  = (const int*)d_in[2];
    const int*   tg_len  = (const int*)d_in[3];
    float* out = (float*)d_out;

    hipMemsetAsync(out, 0, sizeof(float), stream);
    ctc_dp<<<dim3(CB), dim3(64), 0, stream>>>(lp, targets, in_len, tg_len, out);
}

// Round 4
// 440.724 us; speedup vs baseline: 2.7182x; 1.1519x over previous
//
#include <hip/hip_runtime.h>
#include <stdint.h>

// CTC forward NLL, B=32, T=2000, V=1024, S=128, L=2S+1=257.
// Two-phase (round-0 architecture; fused-LDS-streaming abandoned: per-CU
// LDS-DMA return ~16 B/cyc caps one-CU streaming at ~33 GB/s):
// Phase 1 (32000 blocks x 256): stage a ROW-PAIR (8 KB) in LDS, gather the
//   2x129 needed entries, exp+clamp, store PAIR-PACKED labels: lane l holds
//   {row2t[s2l], row2t[s2l+1], row2t+1[s2l], row2t+1[s2l+1]} = 16 B/lane
//   -> phase 2 reads one dwordx4 per lane per row-pair.
// Phase 2 (32 blocks x 1 wave): linear-domain DP, per-lane block-floating-
//   point, DPP neighbor exchange. Register ring of 12 chunks x 3 dwordx4
//   (33 loads = 33 KB/wave in flight), uniform asm s_waitcnt vmcnt(33)
//   pacing, chunks aligned to pair boundaries by handling t=1 as a scalar
//   pre-step. pb row staged once to LDS (8 KB). All ring loads/waits are
//   volatile asm with ring registers tied "+v" (round-0 proven discipline);
//   __syncthreads() + vmcnt(0) drain isolates compiler-managed loads from
//   the counted ring.

#define LOG2E_F 1.4426950408889634f
#define LN2_F   0.6931471805599453f

constexpr int CB = 32;       // batch
constexpr int CT = 2000;     // time
constexpr int CV = 1024;     // vocab
constexpr int CS = 128;      // max target len
constexpr float PMIN = 9.5367431640625e-07f;  // 2^-20: 6-step window >= 2^-120

typedef float f4 __attribute__((ext_vector_type(4)));

__device__ __forceinline__ float pexp(float x) {
    return fmaxf(exp2f(x * LOG2E_F), PMIN);
}

// ---------------- phase 1: row-pair gather ----------------
__global__ __launch_bounds__(256) void ctc_gather2(const float* __restrict__ lp,
                                                   const int* __restrict__ targets,
                                                   float* __restrict__ lab2,
                                                   float* __restrict__ pbuf) {
    __shared__ float rows[2048];             // 8 KB: rows t0, t0+1
    const int bt2 = blockIdx.x;              // b*1000 + t2
    const int tid = threadIdx.x;
    const int b   = bt2 / 1000;
    const int t0  = 2 * (bt2 - b * 1000);
    const f4* src = (const f4*)(lp + ((size_t)b * CT + t0) * CV);
    ((f4*)rows)[tid]       = src[tid];
    ((f4*)rows)[tid + 256] = src[tid + 256];
    __syncthreads();
    if (tid < 64) {
        const int tg0 = targets[b * CS + 2 * tid];
        const int tg1 = targets[b * CS + 2 * tid + 1];
        f4 v;
        v.x = pexp(rows[tg0]);           // row t0,   state 2*tid
        v.y = pexp(rows[tg1]);           // row t0,   state 2*tid+1
        v.z = pexp(rows[1024 + tg0]);    // row t0+1, state 2*tid
        v.w = pexp(rows[1024 + tg1]);    // row t0+1, state 2*tid+1
        ((f4*)lab2)[(size_t)bt2 * 64 + tid] = v;
    } else if (tid == 64) {
        pbuf[(size_t)b * CT + t0] = pexp(rows[0]);
    } else if (tid == 65) {
        pbuf[(size_t)b * CT + t0 + 1] = pexp(rows[1024]);
    }
}

// ---------------- DPP helpers ----------------
__device__ __forceinline__ float dpp_wshr1(float x) {   // lane n <- lane n-1, lane0 <- 0
    return __int_as_float(__builtin_amdgcn_update_dpp(
        0, __float_as_int(x), 0x138, 0xF, 0xF, true));
}
__device__ __forceinline__ int dpp_wshr1_i(int x) {
    return __builtin_amdgcn_update_dpp(0, x, 0x138, 0xF, 0xF, true);
}

// ---------------- DP core ----------------
// R[3] = 3 pair-packed dwordx4: R[p] = {r2p[s0], r2p[s1], r2p+1[s0], r2p+1[s1]}
__device__ __forceinline__ void run6p(const f4 (&R)[3], const float (&pv)[6],
                                      float& a0, float& a1, float& a2, float& a3,
                                      float& aX, float msk1, float msk3, float f) {
#pragma unroll
    for (int u = 0; u < 6; ++u) {
        const float l0 = R[u >> 1][(u & 1) * 2];
        const float l1 = R[u >> 1][(u & 1) * 2 + 1];
        const float pb = pv[u];
        const float u3 = dpp_wshr1(a3) * f;              // old alpha[4i-1], rescaled
        const float n0 = (a0 + u3) * pb;                 // blank 4i
        const float n1 = fmaf(msk1, u3, a1 + a0) * l0;   // label s=2i
        const float n2 = (a2 + a1) * pb;                 // blank 4i+2
        const float n3 = fmaf(msk3, a1, a3 + a2) * l1;   // label s=2i+1
        const float nX = (aX + a3) * pb;                 // cell 256 (lane 63 only valid)
        a0 = n0; a1 = n1; a2 = n2; a3 = n3; aX = nX;
    }
}

__device__ __forceinline__ void renorm(float& a0, float& a1, float& a2,
                                       float& a3, float& aX, int& Sc, float& f) {
    const float m = fmaxf(fmaxf(fmaxf(a0, a1), fmaxf(a2, a3)), aX);
    const bool active = (m > 0.f);
    const int E = active ? (((__float_as_int(m) >> 23) & 0xFF) - 126) : 0;
    const float s = __int_as_float((127 - E) << 23);   // exact 2^-E
    a0 *= s; a1 *= s; a2 *= s; a3 *= s; aX *= s;
    Sc += E;
#pragma unroll
    for (int k = 0; k < 4; ++k) {
        const int scl = dpp_wshr1_i(Sc);
        Sc = active ? Sc : scl;
    }
    int d = dpp_wshr1_i(Sc) - Sc;
    d = min(126, max(-126, d));
    f = __int_as_float((d + 127) << 23);               // exact 2^d
}

// ---------------- ring macros ----------------
// Chunk cc covers rows 2+6cc..7+6cc = pairs 1+3cc..3+3cc. 3 dwordx4/lane.
#define PF3(SLOT, cc) do {                                                          \
    const float* _s = lab_base + (size_t)(1 + 3 * (size_t)(cc)) * 256 + 4 * lane;   \
    asm volatile("global_load_dwordx4 %0, %1, off" : "=v"(rg[SLOT][0]) : "v"(_s));        \
    asm volatile("global_load_dwordx4 %0, %1, off" : "=v"(rg[SLOT][1]) : "v"(_s + 256));  \
    asm volatile("global_load_dwordx4 %0, %1, off" : "=v"(rg[SLOT][2]) : "v"(_s + 512));  \
} while (0)

// Steady state: 36 outstanding (chunks c..c+11); wait to 33 -> chunk c done.
#define WAITC(SLOT)                                                                 \
    asm volatile("s_waitcnt vmcnt(33)"                                              \
                 : "+v"(rg[SLOT][0]), "+v"(rg[SLOT][1]), "+v"(rg[SLOT][2]))

#define SECTION(SLOT) {                                                             \
    PF3(((SLOT) + 11) % 12, min(c + 11, NCm1));                                     \
    WAITC(SLOT);                                                                    \
    const int toff = 2 + 6 * c;                                                     \
    float pv[6];                                                                    \
    pv[0] = pb_lds[toff];     pv[1] = pb_lds[toff + 1];                             \
    pv[2] = pb_lds[toff + 2]; pv[3] = pb_lds[toff + 3];                             \
    pv[4] = pb_lds[toff + 4]; pv[5] = pb_lds[toff + 5];                             \
    run6p(rg[SLOT], pv, a0, a1, a2, a3, aX, msk1, msk3, f);                         \
    renorm(a0, a1, a2, a3, aX, Sc, f);                                              \
    if (++c >= NC) break;                                                           \
}

// ---------------- phase 2: the DP ----------------
__global__ __launch_bounds__(64) void ctc_dp2(
        const float* __restrict__ lab2, const float* __restrict__ pbuf,
        const int* __restrict__ targets, const int* __restrict__ in_len,
        const int* __restrict__ tg_len, float* __restrict__ out) {
    __shared__ float pb_lds[2048];           // 8 KB blank-prob row
    const int b = blockIdx.x;
    const int lane = threadIdx.x;            // 0..63, owns cells 4i..4i+3
    const int Tb = in_len[b];
    const int Sb = tg_len[b];
    const float* lab_base = lab2 + (size_t)b * 1000 * 256;   // pair-packed
    const float* pb_base  = pbuf + (size_t)b * CT;

    const int tg0 = targets[b * CS + 2 * lane];
    const int tg1 = targets[b * CS + 2 * lane + 1];
    const int tgm = dpp_wshr1_i(tg1);        // targets[2i-1] (lane0: 0)
    const float msk1 = (tg0 != tgm) ? 1.f : 0.f;
    const float msk3 = (tg1 != tg0) ? 1.f : 0.f;
    (void)tg0; (void)tg1;

    // stage pb row to LDS: 8 x 256-float strips (last overlapped, in-bounds)
#pragma unroll
    for (int k = 0; k < 8; ++k) {
        const int start = (k * 256 + 256 <= CT) ? k * 256 : CT - 256;
        ((f4*)(pb_lds + start))[lane] = ((const f4*)(pb_base + start))[lane];
    }

    // t=0 init: alpha[0]=p_blank, alpha[1]=p(label 0); row 0 = pair 0 even half
    float a0 = 0.f, a1 = 0.f, a2 = 0.f, a3 = 0.f, aX = 0.f;
    {
        const float pb0 = pb_base[0];
        const float pl0 = lab_base[0];       // lane0 slot: pair0 floats[0] = row0,state1
        if (lane == 0) { a0 = pb0; a1 = pl0; }
    }
    int Sc = 0;
    float f = 1.f;
    renorm(a0, a1, a2, a3, aX, Sc, f);

    // t=1 scalar pre-step (odd half of pair 0) so 6-row chunks start at t=2
    if (Tb > 1) {
        const float2 lb = *(const float2*)(lab_base + 4 * lane + 2);
        const float pb = pb_base[1];
        const float u3 = dpp_wshr1(a3) * f;
        const float n0 = (a0 + u3) * pb;
        const float n1 = fmaf(msk1, u3, a1 + a0) * lb.x;
        const float n2 = (a2 + a1) * pb;
        const float n3 = fmaf(msk3, a1, a3 + a2) * lb.y;
        const float nX = (aX + a3) * pb;
        a0 = n0; a1 = n1; a2 = n2; a3 = n3; aX = nX;
        renorm(a0, a1, a2, a3, aX, Sc, f);
    }

    const int NC = (Tb >= 2) ? (Tb - 2) / 6 : 0;   // 6-row chunks from t=2
    const int NCm1 = NC - 1;

    // Fence all compiler-managed loads (pb staging, init, pre-step) out of
    // the counted ring: barrier forces a full drain and blocks migration.
    __syncthreads();

    f4 rg[12][3];                            // 144-VGPR register ring
    if (NC >= 1) {
        asm volatile("s_waitcnt vmcnt(0)");
        PF3(0, 0);                 PF3(1, min(1, NCm1));
        PF3(2, min(2, NCm1));      PF3(3, min(3, NCm1));
        PF3(4, min(4, NCm1));      PF3(5, min(5, NCm1));
        PF3(6, min(6, NCm1));      PF3(7, min(7, NCm1));
        PF3(8, min(8, NCm1));      PF3(9, min(9, NCm1));
        PF3(10, min(10, NCm1));    // 33 outstanding
        int c = 0;
        while (true) {
            SECTION(0)  SECTION(1)  SECTION(2)  SECTION(3)
            SECTION(4)  SECTION(5)  SECTION(6)  SECTION(7)
            SECTION(8)  SECTION(9)  SECTION(10) SECTION(11)
        }
        // Drain stragglers; keep ring registers alive past the drain so late
        // completions cannot clobber reallocated registers.
        asm volatile("s_waitcnt vmcnt(0)");
        asm volatile("" ::
            "v"(rg[0][0]), "v"(rg[0][1]), "v"(rg[0][2]),
            "v"(rg[1][0]), "v"(rg[1][1]), "v"(rg[1][2]),
            "v"(rg[2][0]), "v"(rg[2][1]), "v"(rg[2][2]),
            "v"(rg[3][0]), "v"(rg[3][1]), "v"(rg[3][2]),
            "v"(rg[4][0]), "v"(rg[4][1]), "v"(rg[4][2]),
            "v"(rg[5][0]), "v"(rg[5][1]), "v"(rg[5][2]));
        asm volatile("" ::
            "v"(rg[6][0]), "v"(rg[6][1]), "v"(rg[6][2]),
            "v"(rg[7][0]), "v"(rg[7][1]), "v"(rg[7][2]),
            "v"(rg[8][0]), "v"(rg[8][1]), "v"(rg[8][2]),
            "v"(rg[9][0]), "v"(rg[9][1]), "v"(rg[9][2]),
            "v"(rg[10][0]), "v"(rg[10][1]), "v"(rg[10][2]),
            "v"(rg[11][0]), "v"(rg[11][1]), "v"(rg[11][2]));
    }

    // tail: t = 2+6*NC .. Tb-1 (<=5 steps); compiler-managed loads, ring drained
    for (int t = 2 + 6 * NC; t < Tb; ++t) {
        const float2 lb = *(const float2*)(lab_base
                              + (size_t)(t >> 1) * 256 + 4 * lane + 2 * (t & 1));
        const float pb = pb_lds[t];
        const float u3 = dpp_wshr1(a3) * f;
        const float n0 = (a0 + u3) * pb;
        const float n1 = fmaf(msk1, u3, a1 + a0) * lb.x;
        const float n2 = (a2 + a1) * pb;
        const float n3 = fmaf(msk3, a1, a3 + a2) * lb.y;
        const float nX = (aX + a3) * pb;
        a0 = n0; a1 = n1; a2 = n2; a3 = n3; aX = nX;
    }

    // final: ll = log(alpha[2*Sb] + alpha[2*Sb-1]); per-lane scales -> LSE
    const int idx1 = 2 * Sb;
    const int idx2 = (idx1 - 1 > 0) ? (idx1 - 1) : 0;
    const int b4 = 4 * lane;
    float cres = 0.f;
    if (b4 + 0 == idx1 || b4 + 0 == idx2) cres += a0;
    if (b4 + 1 == idx1 || b4 + 1 == idx2) cres += a1;
    if (b4 + 2 == idx1 || b4 + 2 == idx2) cres += a2;
    if (b4 + 3 == idx1 || b4 + 3 == idx2) cres += a3;
    if (lane == 63 && (idx1 == 256 || idx2 == 256)) cres += aX;

    float l2 = (cres > 0.f) ? (log2f(cres) + (float)Sc) : -1e30f;
    float M = l2;
#pragma unroll
    for (int m = 1; m < 64; m <<= 1) M = fmaxf(M, __shfl_xor(M, m, 64));
    float e = (cres > 0.f) ? exp2f(l2 - M) : 0.f;
#pragma unroll
    for (int m = 1; m < 64; m <<= 1) e += __shfl_xor(e, m, 64);
    if (lane == 0) {
        const float ll = (M + log2f(e)) * LN2_F;
        atomicAdd(out, -ll);
    }
}

extern "C" void kernel_launch(void* const* d_in, const int* in_sizes, int n_in,
                              void* d_out, int out_size, void* d_ws, size_t ws_size,
                              hipStream_t stream) {
    (void)in_sizes; (void)n_in; (void)out_size; (void)ws_size;
    const float* lp      = (const float*)d_in[0];
    const int*   targets = (const int*)d_in[1];
    const int*   in_len  = (const int*)d_in[2];
    const int*   tg_len  = (const int*)d_in[3];
    float* out   = (float*)d_out;
    float* lab2  = (float*)d_ws;                             // 32.77 MB pair-packed
    float* pbuf  = lab2 + (size_t)CB * 1000 * 256;           // +256 KB

    hipMemsetAsync(out, 0, sizeof(float), stream);
    ctc_gather2<<<dim3(CB * (CT / 2)), dim3(256), 0, stream>>>(lp, targets, lab2, pbuf);
    ctc_dp2<<<dim3(CB), dim3(64), 0, stream>>>(lab2, pbuf, targets, in_len, tg_len, out);
}